// Round 5
// baseline (3169.894 us; speedup 1.0000x reference)
//
#include <hip/hip_runtime.h>

#define N_NODES 500000
typedef unsigned int u32;
typedef unsigned short u16;

// ===========================================================================
// R14: scatter-orientation rewrite (src-sorted edges + fire-and-forget
// global atomics).
// Evidence R9/R10/R13: gather layers pinned at ~6.9 cyc/edge/CU regardless
// of occupancy (56%/38%) and per-wave ILP (VGPR 12/24/52) -> per-CU MSHR
// wall: each random gather holds an L1 MSHR for the full ~350cy L2/L3
// round trip (~64 MSHRs -> 0.18 edges/cyc/CU == measured). Returnless
// atomics don't dwell in MSHRs -> invert: sort by SRC, stage src values in
// LDS (coalesced), scatter with unsafeAtomicAdd (global_atomic_add_f32,
// FAF) to per-dst accumulators. Node passes do rsqrt/MLP coalesced.
//   rec = src_local9<<19 | dst19   per 512-node SRC bucket.
// ===========================================================================
#define NPB    512
#define NBUCK  ((N_NODES + NPB - 1) / NPB)   // 977
#define CAP    20480          // region capacity; E[fill]=16384, sigma~128 (32σ)
#define CH     8192           // edges per scatter chunk/WG
#define EPT    8              // edges per thread in scatter (CH / 1024)
#define STB    1024           // scatter block
#define LTB    512            // layer/deg block
#define DST19  0x7FFFFu

typedef unsigned int v4u __attribute__((ext_vector_type(4)));
__device__ inline int  nt1i(const int* p) { return __builtin_nontemporal_load(p); }
__device__ inline u32  nt1u(const u32* p) { return __builtin_nontemporal_load(p); }
__device__ inline v4u  nt4u(const u32* p) { return __builtin_nontemporal_load((const v4u*)p); }

// ---- fused scatter (R9 machinery, keyed by SRC bucket):
//      edges register-cached; LDS histogram + scan + presort; coalesced run
//      writes into fixed bucket regions.
__global__ __launch_bounds__(STB) void k_scatter_fused(
        const int* __restrict__ src, const int* __restrict__ dst, int E,
        u32* __restrict__ cur_g, u32* __restrict__ rec) {
    __shared__ u32 srec[CH];        // 32 KB
    __shared__ u16 sbk[CH];         // 16 KB
    __shared__ u32 hist[NBUCK];     // 3.9 KB
    __shared__ u32 sc[1024];        // 4 KB
    __shared__ u32 scn_ex[NBUCK];
    __shared__ u32 cur2[NBUCK];
    __shared__ u32 gbase[NBUCK];
    int tid = threadIdx.x, bid = blockIdx.x;
    for (int b = tid; b < NBUCK; b += STB) hist[b] = 0;
    __syncthreads();
    int e0 = bid * CH, e1 = min(E, e0 + CH), n = e1 - e0;
    // load edges into registers (coalesced), histogram on SRC bucket
    u32 dv[EPT], sv[EPT];
#pragma unroll
    for (int k = 0; k < EPT; ++k) {
        int e = e0 + (k << 10) + tid;
        if (e < e1) {
            dv[k] = (u32)nt1i(dst + e);
            sv[k] = (u32)nt1i(src + e);
            atomicAdd(&hist[sv[k] >> 9], 1u);
        }
    }
    __syncthreads();
    // scan over 1024 slots (Hillis-Steele)
    sc[tid] = (tid < NBUCK) ? hist[tid] : 0u;
    __syncthreads();
    for (int off = 1; off < 1024; off <<= 1) {
        u32 t = (tid >= off) ? sc[tid - off] : 0u;
        __syncthreads();
        sc[tid] += t;
        __syncthreads();
    }
    if (tid < NBUCK) {
        u32 ex = sc[tid] - hist[tid];
        scn_ex[tid] = ex;
        cur2[tid] = ex;
        gbase[tid] = hist[tid] ? atomicAdd(&cur_g[tid], hist[tid]) : 0u;
    }
    __syncthreads();
    // presort into LDS from registers: rec = src_local<<19 | dst
    #pragma unroll
    for (int k = 0; k < EPT; ++k) {
        int e = e0 + (k << 10) + tid;
        if (e < e1) {
            u32 b = sv[k] >> 9;
            u32 p = atomicAdd(&cur2[b], 1u);
            srec[p] = ((sv[k] & (NPB - 1u)) << 19) | dv[k];
            sbk[p] = (u16)b;
        }
    }
    __syncthreads();
    // coalesced run writes into bucket regions
    for (int p = tid; p < n; p += STB) {
        u32 b = sbk[p];
        u32 slot = gbase[b] + ((u32)p - scn_ex[b]);
        rec[(size_t)b * CAP + slot] = srec[p];
    }
}

// ---- deg via FAF u32 atomics: deg[dst] += 1
__global__ __launch_bounds__(LTB) void k_deg_scatter(
        const u32* __restrict__ rec, const u32* __restrict__ cnt_g,
        u32* __restrict__ deg) {
    int tid = threadIdx.x, bid = blockIdx.x;
    const u32* r0 = rec + (size_t)bid * CAP;
    u32 n = cnt_g[bid];
    u32 nv = n >> 2;
    for (u32 i = tid; i < nv; i += LTB) {
        v4u r = nt4u(r0 + ((size_t)i << 2));
        atomicAdd(&deg[r.x & DST19], 1u);
        atomicAdd(&deg[r.y & DST19], 1u);
        atomicAdd(&deg[r.z & DST19], 1u);
        atomicAdd(&deg[r.w & DST19], 1u);
    }
    for (u32 e = (nv << 2) + tid; e < n; e += LTB)
        atomicAdd(&deg[nt1u(r0 + e) & DST19], 1u);
}

// ---- node pass 1: dis = rsqrt(deg+1), m1 = dis*x
__global__ void k_node1(const u32* __restrict__ deg, const float* __restrict__ x,
                        float* __restrict__ dis, float* __restrict__ m1, int N) {
    int i = blockIdx.x * blockDim.x + threadIdx.x;
    if (i < N) {
        float r = rsqrtf((float)(deg[i] + 1u));   // +1 self-loop
        dis[i] = r;
        m1[i] = r * x[i];
    }
}

// ---- layer-1 scatter: stage m1[src tile] in LDS; FAF accg[dst] += m1[src]
__global__ __launch_bounds__(LTB) void k_l1_scatter(
        const u32* __restrict__ rec, const u32* __restrict__ cnt_g,
        const float* __restrict__ m1, float* __restrict__ accg) {
    __shared__ float sm[NPB];
    int tid = threadIdx.x, bid = blockIdx.x;
    int node0 = bid << 9;
    int nn = min(NPB, N_NODES - node0);
    for (int l = tid; l < nn; l += LTB) sm[l] = m1[node0 + l];
    __syncthreads();
    const u32* r0 = rec + (size_t)bid * CAP;
    u32 n = cnt_g[bid];
    u32 nv = n >> 2;
    for (u32 i = tid; i < nv; i += LTB) {
        v4u r = nt4u(r0 + ((size_t)i << 2));
        unsafeAtomicAdd(&accg[r.x & DST19], sm[r.x >> 19]);
        unsafeAtomicAdd(&accg[r.y & DST19], sm[r.y >> 19]);
        unsafeAtomicAdd(&accg[r.z & DST19], sm[r.z >> 19]);
        unsafeAtomicAdd(&accg[r.w & DST19], sm[r.w >> 19]);
    }
    for (u32 e = (nv << 2) + tid; e < n; e += LTB) {
        u32 r = nt1u(r0 + e);
        unsafeAtomicAdd(&accg[r & DST19], sm[r >> 19]);
    }
}

// ---- node pass 2: s = d*(accg+m1); MLP; h2m = d*h2
__global__ void k_node2(const float* __restrict__ dis, const float* __restrict__ m1,
                        const float* __restrict__ accg,
                        const float* __restrict__ W1, const float* __restrict__ b1,
                        const float* __restrict__ W2, const float* __restrict__ b2,
                        float2* __restrict__ h2m, int N) {
    int i = blockIdx.x * blockDim.x + threadIdx.x;
    if (i >= N) return;
    float d = dis[i];
    float s = d * (accg[i] + m1[i]);
    float a0 = 0.f, a1 = 0.f;
#pragma unroll
    for (int k = 0; k < 8; ++k) {
        float h = fmaxf(W1[k] * s + b1[k], 0.f);
        a0 += h * W2[2 * k + 0];
        a1 += h * W2[2 * k + 1];
    }
    h2m[i] = make_float2(d * a0, d * a1);       // dis[src]*h2
}

// ---- layer-2 scatter: stage h2m[src tile] in LDS; FAF acc2[dst] += h2m[src]
__global__ __launch_bounds__(LTB) void k_l2_scatter(
        const u32* __restrict__ rec, const u32* __restrict__ cnt_g,
        const float2* __restrict__ h2m, float* __restrict__ acc2) {
    __shared__ float2 sm[NPB];
    int tid = threadIdx.x, bid = blockIdx.x;
    int node0 = bid << 9;
    int nn = min(NPB, N_NODES - node0);
    for (int l = tid; l < nn; l += LTB) sm[l] = h2m[node0 + l];
    __syncthreads();
    const u32* r0 = rec + (size_t)bid * CAP;
    u32 n = cnt_g[bid];
    u32 nv = n >> 2;
    for (u32 i = tid; i < nv; i += LTB) {
        v4u r = nt4u(r0 + ((size_t)i << 2));
        float2 v0 = sm[r.x >> 19];
        float2 v1 = sm[r.y >> 19];
        float2 v2 = sm[r.z >> 19];
        float2 v3 = sm[r.w >> 19];
        u32 d0 = (r.x & DST19) << 1, d1 = (r.y & DST19) << 1;
        u32 d2 = (r.z & DST19) << 1, d3 = (r.w & DST19) << 1;
        unsafeAtomicAdd(&acc2[d0], v0.x); unsafeAtomicAdd(&acc2[d0 + 1], v0.y);
        unsafeAtomicAdd(&acc2[d1], v1.x); unsafeAtomicAdd(&acc2[d1 + 1], v1.y);
        unsafeAtomicAdd(&acc2[d2], v2.x); unsafeAtomicAdd(&acc2[d2 + 1], v2.y);
        unsafeAtomicAdd(&acc2[d3], v3.x); unsafeAtomicAdd(&acc2[d3 + 1], v3.y);
    }
    for (u32 e = (nv << 2) + tid; e < n; e += LTB) {
        u32 r = nt1u(r0 + e);
        float2 v = sm[r >> 19];
        u32 d = (r & DST19) << 1;
        unsafeAtomicAdd(&acc2[d], v.x);
        unsafeAtomicAdd(&acc2[d + 1], v.y);
    }
}

// ---- final node pass: out = b2 + d*(acc2 + h2m)   (self term = d*h2m)
__global__ void k_nodeO(const float* __restrict__ dis,
                        const float2* __restrict__ h2m,
                        const float2* __restrict__ acc2,
                        const float* __restrict__ b2,
                        float2* __restrict__ out, int N) {
    int i = blockIdx.x * blockDim.x + threadIdx.x;
    if (i >= N) return;
    float d = dis[i];
    float2 a = acc2[i], h = h2m[i];
    out[i] = make_float2(b2[0] + d * (a.x + h.x), b2[1] + d * (a.y + h.y));
}

// ===========================================================================
// Fallback path (R1): global atomics — only if ws too small (needs 10 MB).
// ===========================================================================
__global__ void f_count_deg(const int* __restrict__ dst, int E,
                            u32* __restrict__ deg) {
    int i = blockIdx.x * blockDim.x + threadIdx.x;
    int stride = gridDim.x * blockDim.x;
    for (int e = i; e < E; e += stride) atomicAdd(&deg[dst[e]], 1u);
}
__global__ void f_dis_sinit(const u32* __restrict__ deg, const float* __restrict__ x,
                            float* __restrict__ dis, float* __restrict__ s, int N) {
    int i = blockIdx.x * blockDim.x + threadIdx.x;
    if (i < N) {
        float r = rsqrtf((float)(deg[i] + 1u));
        dis[i] = r;
        s[i] = r * r * x[i];
    }
}
__global__ void f_agg1(const int* __restrict__ src, const int* __restrict__ dst,
                       int E, const float* __restrict__ dis,
                       const float* __restrict__ x, float* __restrict__ s) {
    int i = blockIdx.x * blockDim.x + threadIdx.x;
    int stride = gridDim.x * blockDim.x;
    for (int e = i; e < E; e += stride) {
        int sj = src[e], dj = dst[e];
        atomicAdd(&s[dj], dis[sj] * dis[dj] * x[sj]);
    }
}
__global__ void f_node2(const float* __restrict__ s, const float* __restrict__ dis,
                        const float* __restrict__ W1, const float* __restrict__ b1,
                        const float* __restrict__ W2, const float* __restrict__ b2,
                        float2* __restrict__ h2, float2* __restrict__ out, int N) {
    int i = blockIdx.x * blockDim.x + threadIdx.x;
    if (i >= N) return;
    float si = s[i];
    float a0 = 0.f, a1 = 0.f;
#pragma unroll
    for (int k = 0; k < 8; ++k) {
        float hk = fmaxf(W1[k] * si + b1[k], 0.f);
        a0 += hk * W2[2 * k + 0];
        a1 += hk * W2[2 * k + 1];
    }
    h2[i] = make_float2(a0, a1);
    float r2 = dis[i] * dis[i];
    out[i] = make_float2(b2[0] + r2 * a0, b2[1] + r2 * a1);
}
__global__ void f_agg2(const int* __restrict__ src, const int* __restrict__ dst,
                       int E, const float* __restrict__ dis,
                       const float2* __restrict__ h2, float* __restrict__ out) {
    int i = blockIdx.x * blockDim.x + threadIdx.x;
    int stride = gridDim.x * blockDim.x;
    for (int e = i; e < E; e += stride) {
        int sj = src[e], dj = dst[e];
        float nm = dis[sj] * dis[dj];
        float2 v = h2[sj];
        atomicAdd(&out[2 * dj + 0], nm * v.x);
        atomicAdd(&out[2 * dj + 1], nm * v.y);
    }
}

// ===========================================================================
extern "C" void kernel_launch(void* const* d_in, const int* in_sizes, int n_in,
                              void* d_out, int out_size, void* d_ws, size_t ws_size,
                              hipStream_t stream) {
    const float* x  = (const float*)d_in[0];
    const int*   ei = (const int*)d_in[1];   // [2,E]: src row, then dst row
    const float* W1 = (const float*)d_in[2];
    const float* b1 = (const float*)d_in[3];
    const float* W2 = (const float*)d_in[4];
    const float* b2 = (const float*)d_in[5];

    const int N = N_NODES;
    const int E = in_sizes[1] / 2;
    const int* src = ei;
    const int* dst = ei + E;
    float* out = (float*)d_out;
    char* ws = (char*)d_ws;

    // ---- fast-path workspace ----
    size_t off = 0;
    auto take = [&](size_t bytes) { size_t o = off; off = (off + bytes + 255) & ~(size_t)255; return o; };
    // zeroed region: [cur_g | deg | accg | acc2] contiguous
    size_t off_cur  = take(NBUCK * 4);
    size_t off_deg  = take((size_t)N * 4);
    size_t off_accg = take((size_t)N * 4);
    size_t off_acc2 = take((size_t)N * 8);
    size_t zero_end = off_acc2 + (size_t)N * 8;
    size_t off_dis  = take((size_t)N * 4);
    size_t off_m1   = take((size_t)N * 4);
    size_t off_h2m  = take((size_t)N * 8);
    size_t off_rec  = take((size_t)NBUCK * CAP * 4 + 16);   // ~80 MB
    size_t need     = off;

    if (ws_size >= need) {
        u32* cur_g  = (u32*)(ws + off_cur);
        u32* deg    = (u32*)(ws + off_deg);
        float* accg = (float*)(ws + off_accg);
        float* acc2 = (float*)(ws + off_acc2);
        float* dis  = (float*)(ws + off_dis);
        float* m1   = (float*)(ws + off_m1);
        float2* h2m = (float2*)(ws + off_h2m);
        u32* rec    = (u32*)(ws + off_rec);

        hipMemsetAsync(ws + off_cur, 0, zero_end - off_cur, stream);
        const int nchunks = (E + CH - 1) / CH;
        int nodeBlocks = (N + 255) / 256;
        k_scatter_fused<<<nchunks, STB, 0, stream>>>(src, dst, E, cur_g, rec);
        k_deg_scatter  <<<NBUCK,   LTB, 0, stream>>>(rec, cur_g, deg);
        k_node1        <<<nodeBlocks, 256, 0, stream>>>(deg, x, dis, m1, N);
        k_l1_scatter   <<<NBUCK,   LTB, 0, stream>>>(rec, cur_g, m1, accg);
        k_node2        <<<nodeBlocks, 256, 0, stream>>>(dis, m1, accg,
                                                        W1, b1, W2, b2, h2m, N);
        k_l2_scatter   <<<NBUCK,   LTB, 0, stream>>>(rec, cur_g, h2m, acc2);
        k_nodeO        <<<nodeBlocks, 256, 0, stream>>>(dis, h2m, (float2*)acc2,
                                                        b2, (float2*)out, N);
        return;
    }

    // ---- fallback: R1 global-atomic path (10 MB ws) ----
    u32* deg    = (u32*)(ws);
    float* dis  = (float*)(ws + (size_t)N * 4);
    float* s    = (float*)(ws + (size_t)N * 8);
    float2* h2  = (float2*)(ws + (size_t)N * 12);
    hipMemsetAsync(deg, 0, (size_t)N * 4, stream);
    int nodeBlocks = (N + 255) / 256;
    int edgeBlocks = (E + 255) / 256;
    f_count_deg<<<edgeBlocks, 256, 0, stream>>>(dst, E, deg);
    f_dis_sinit<<<nodeBlocks, 256, 0, stream>>>(deg, x, dis, s, N);
    f_agg1     <<<edgeBlocks, 256, 0, stream>>>(src, dst, E, dis, x, s);
    f_node2    <<<nodeBlocks, 256, 0, stream>>>(s, dis, W1, b1, W2, b2, h2,
                                                (float2*)out, N);
    f_agg2     <<<edgeBlocks, 256, 0, stream>>>(src, dst, E, dis, h2, out);
}